// Round 25
// baseline (82.172 us; speedup 1.0000x reference)
//
#include <hip/hip_runtime.h>

#define HH    1024
#define WW    1024
#define KS    15
#define PAD   7
#define CELL  256
#define BX    64            // x-width per block (4 waves x 16)
#define TROWS 142           // tile rows (128-row strip + 2*PAD)
#define TCOLS 80            // staged halves per row (160B rows)
#define NITER 16            // 2 strips x 8 patches (per column)
#define CHN   18            // 2 strips x 9 chunks (8 full + 14-row tail each)
#define NWG   768           // 3 blocks/CU exactly; 2 plane-columns per block
#define AWS_CELL_BYTES (KS * 1024)   // 15 fragments x 1KB

typedef _Float16     f16x8 __attribute__((ext_vector_type(8)));
typedef _Float16     f16x4 __attribute__((ext_vector_type(4)));
typedef float        f32x4 __attribute__((ext_vector_type(4)));
typedef unsigned int u32x4 __attribute__((ext_vector_type(4)));

// Barrier with LDS ordering only (no vmcnt(0) drain).
static __device__ __forceinline__ void light_barrier() {
    asm volatile("s_waitcnt lgkmcnt(0)\n\ts_barrier" ::: "memory");
}

// ---- prep: materialize normalized Toeplitz A fragments per cell into d_ws ----
__global__ __launch_bounds__(256) void pb_prep_kernel(
    const float* __restrict__ kern, unsigned int* __restrict__ aws)
{
    const int cell = blockIdx.x;           // cj*4+ci
    const int tid  = threadIdx.x;
    const int lane = tid & 63;
    const float* kp = kern + cell * (KS * KS);

    float s = 0.f;
    #pragma unroll
    for (int i = 0; i < 4; ++i) {
        int t = lane + 64 * i;
        s += (t < KS * KS) ? kp[t] : 0.f;
    }
    #pragma unroll
    for (int m = 1; m < 64; m <<= 1) s += __shfl_xor(s, m, 64);
    const float inv = 1.0f / (s + 1e-12f);

    const int i  = tid >> 4;               // x-position (A row)
    const int k2 = tid & 15;               // half-pair index
    unsigned int* wp = aws + cell * (AWS_CELL_BYTES / 4) + tid;

    for (int dy = 0; dy < KS; ++dy) {
        float v0 = 0.f, v1 = 0.f;
        int dx0 = 2 * k2 - i - 1;          // A[i][k] = kh[k-i-1]
        int dx1 = dx0 + 1;
        if (dx0 >= 0 && dx0 < KS) v0 = kp[dy * KS + dx0] * inv;
        if (dx1 >= 0 && dx1 < KS) v1 = kp[dy * KS + dx1] * inv;
        f16x4 h; h[0] = (_Float16)v0; h[1] = (_Float16)v1; h[2] = 0; h[3] = 0;
        unsigned long long u = __builtin_bit_cast(unsigned long long, h);
        wp[dy * 256] = (unsigned int)u;
    }
}

// ---- main: R22/R24 body, PERSISTENT 768-block grid (3 blocks/CU uniform).
// 1536 blocks at a 4-blocks/CU VGPR cap ran as dispatch rounds of 4 then 2
// (measured 31% avg occupancy = half-speed tail round). 768 = 3x256: every
// CU holds 3 blocks for the whole kernel. Each block runs TWO plane-columns
// (planes sp and sp+12, same x-strip & cell -> af loaded once). XCD swizzle
// on 768 keeps the contiguous-plane L2 locality that won R22.
__global__ __launch_bounds__(256, 4) void pb_mfma_kernel(
    const float* __restrict__ x,
    const unsigned int* __restrict__ aws,
    float* __restrict__ out)
{
    __shared__ __align__(16) _Float16 s_tile[TROWS * TCOLS];   // 22720 B

    const int tid  = threadIdx.x;
    const int lane = tid & 63;
    const int w    = tid >> 6;           // wave id: x sub-block
    const int g    = lane >> 4;          // k-group 0..3
    const int cc   = lane & 15;          // A-row / B-col index

    // T1 swizzle: bijective for NWG % 8 == 0 (per-XCD chunks of 96 ids)
    const int bid = blockIdx.x;
    const int sw  = (bid & 7) * (NWG / 8) + (bid >> 3);
    const int sbx = sw & 15;             // 16 x-strips
    const int sby = (sw >> 4) & 3;       // 4 cell-rows
    const int sp  = sw >> 6;             // 12 plane-pairs

    const int bx0 = sbx * BX;
    const int ci  = sbx >> 2;            // cell col
    const int cj  = sby;                 // cell row

    const int cellx0 = ci * CELL;
    const int celly0 = cj * CELL, celly1 = celly0 + CELL - 1;

    // ---- A fragments: loaded ONCE, shared by both plane-columns ----
    const u32x4* ap = (const u32x4*)(aws + (cj * 4 + ci) * (AWS_CELL_BYTES / 4))
                      + cc * 4 + g;
    u32x4 af[KS];
    #pragma unroll
    for (int dy = 0; dy < KS; ++dy) af[dy] = ap[dy * 64];
    #pragma unroll
    for (int dy = 0; dy < KS; ++dy) asm volatile("" : "+v"(af[dy]));

    #pragma unroll 1
    for (int it = 0; it < 2; ++it) {
        const int bc = sp + it * 12;     // plane (b*c)
        const float* plane = x + (size_t)bc * HH * WW;

        // ---- staging helpers ----
        auto stage_addr = [&](int strip, int lc, int idx) -> const float* {
            int r20  = idx / 20;
            int c4   = idx - r20 * 20;
            int row  = lc * 16 + r20;                   // tile row 0..141
            int gy   = min(max(celly0 + strip * 128 - PAD + row, celly0), celly1);
            int gx0  = bx0 - 8 + 4 * c4;
            int gx0c = min(max(gx0, cellx0), cellx0 + CELL - 4);
            return plane + (size_t)gy * WW + gx0c;
        };
        auto write_group = [&](int lc, int idx, float4 v) {
            int r20 = idx / 20;
            int c4  = idx - r20 * 20;
            int row = lc * 16 + r20;
            int gx0 = bx0 - 8 + 4 * c4;
            bool lo = gx0 <  cellx0;
            bool hi = gx0 >  cellx0 + CELL - 4;
            float e0 = hi ? v.w : v.x;
            float e1 = lo ? v.x : (hi ? v.w : v.y);
            float e2 = lo ? v.x : (hi ? v.w : v.z);
            float e3 = lo ? v.x : v.w;
            f16x4 h;
            h[0] = (_Float16)e0; h[1] = (_Float16)e1;
            h[2] = (_Float16)e2; h[3] = (_Float16)e3;
            *(f16x4*)(s_tile + row * TCOLS + 4 * c4) = h;   // ds_write_b64
        };
        auto issue_chunk = [&](int c, float4& v0, float4& v1, bool& h1) {
            int strip = c >= 9;
            int lc    = c - 9 * strip;
            int ng    = (lc == 8) ? 280 : 320;
            v0 = *(const float4*)stage_addr(strip, lc, tid);
            h1 = 256 + tid < ng;
            if (h1) v1 = *(const float4*)stage_addr(strip, lc, 256 + tid);
        };
        auto write_chunk = [&](int c, float4 v0, float4 v1, bool h1) {
            int strip = c >= 9;
            int lc    = c - 9 * strip;
            (void)strip;
            write_group(lc, tid, v0);
            if (h1) write_group(lc, 256 + tid, v1);
        };

        // ---- prologue: stage chunks 0..2; issue 3,4 as 2-deep pending ----
        // (it=1 reuses the tile; all waves passed the it=0 epilogue barrier,
        // and chunk 0..2 writes land before the light_barrier below.)
        {
            float4 a0, a1, b0, b1, c0, c1; bool ha1, hb1, hc1;
            issue_chunk(0, a0, a1, ha1);
            issue_chunk(1, b0, b1, hb1);
            issue_chunk(2, c0, c1, hc1);
            write_chunk(0, a0, a1, ha1);
            write_chunk(1, b0, b1, hb1);
            write_chunk(2, c0, c1, hc1);
        }
        float4 pA0, pA1, pB0, pB1; bool hA1, hB1;
        issue_chunk(3, pA0, pA1, hA1);
        issue_chunk(4, pB0, pB1, hB1);
        light_barrier();

        // ---- rolling main loop: 16 iterations (2 strips x 8 patches) ----
        const _Float16* bbase = s_tile + cc * TCOLS + w * 16 + g * 8;
        float* oplane = out + (size_t)bc * HH * WW;

        #pragma unroll
        for (int t = 0; t < NITER; ++t) {
            const int strip = t >> 3;
            const int jpl   = t & 7;

            // issue chunk t+5 (written at iter t+2)
            float4 n0 = {0,0,0,0}, n1 = {0,0,0,0}; bool hn1 = false;
            if (t + 5 < CHN) issue_chunk(t + 5, n0, n1, hn1);

            // compute patch: reads tile rows 16*jpl .. 16*jpl+30
            __builtin_amdgcn_s_setprio(1);
            f32x4 acc0 = {0.f, 0.f, 0.f, 0.f};
            f32x4 acc1 = {0.f, 0.f, 0.f, 0.f};
            #pragma unroll
            for (int dy = 0; dy < KS; ++dy) {
                f16x8 b = *(const f16x8*)(bbase + (16 * jpl + dy) * TCOLS);
                if (dy & 1)
                    acc1 = __builtin_amdgcn_mfma_f32_16x16x32_f16(
                               __builtin_bit_cast(f16x8, af[dy]), b, acc1, 0, 0, 0);
                else
                    acc0 = __builtin_amdgcn_mfma_f32_16x16x32_f16(
                               __builtin_bit_cast(f16x8, af[dy]), b, acc0, 0, 0, 0);
            }
            __builtin_amdgcn_s_setprio(0);
            f32x4 r = acc0 + acc1;
            // D: col=lane&15 (image row), row=4*(lane>>4)+e (x position)
            float* op = oplane
                      + (size_t)(celly0 + strip * 128 + 16 * jpl + cc) * WW
                      + bx0 + 16 * w + 4 * g;
            *(f32x4*)op = r;   // rides across light barriers, no drain

            // land pending-oldest chunk t+3 (rows disjoint from patch t reads)
            if (t + 3 < CHN) write_chunk(t + 3, pA0, pA1, hA1);
            light_barrier();

            // rotate pending
            pA0 = pB0; pA1 = pB1; hA1 = hB1;
            pB0 = n0;  pB1 = n1;  hB1 = hn1;
        }
    }
}

extern "C" void kernel_launch(void* const* d_in, const int* in_sizes, int n_in,
                              void* d_out, int out_size, void* d_ws, size_t ws_size,
                              hipStream_t stream) {
    (void)in_sizes; (void)n_in; (void)ws_size; (void)out_size;
    const float* x    = (const float*)d_in[0];
    const float* kern = (const float*)d_in[1];
    float* out        = (float*)d_out;
    unsigned int* aws = (unsigned int*)d_ws;   // 16 cells x 15 KiB = 240 KiB

    pb_prep_kernel<<<16, 256, 0, stream>>>(kern, aws);
    pb_mfma_kernel<<<NWG, 256, 0, stream>>>(x, aws, out);   // persistent, swizzled
}

// Round 26
// 48.170 us; speedup vs baseline: 1.7059x; 1.7059x over previous
//
#include <hip/hip_runtime.h>

#define HH    1024
#define WW    1024
#define KS    15
#define PAD   7
#define CELL  256
#define BX    64            // x-width per block (4 waves x 16)
#define TROWS 142           // tile rows (128-row strip + 2*PAD)
#define TCOLS 80            // staged halves per row (160B rows)
#define NITER 16            // 2 strips x 8 patches
#define CHN   18            // 2 strips x 9 chunks (8 full + 14-row tail each)
#define NWG   (16 * 4 * 24) // 1536 blocks, % 8 == 0 -> simple bijective swizzle
#define AWS_CELL_BYTES (KS * 1024)   // 15 fragments x 1KB

typedef _Float16     f16x8 __attribute__((ext_vector_type(8)));
typedef _Float16     f16x4 __attribute__((ext_vector_type(4)));
typedef float        f32x4 __attribute__((ext_vector_type(4)));
typedef unsigned int u32x4 __attribute__((ext_vector_type(4)));

// Barrier with LDS ordering only (no vmcnt(0) drain): output stores and
// prefetch loads ride across; ds_write data dependency gives precise vmcnt.
static __device__ __forceinline__ void light_barrier() {
    asm volatile("s_waitcnt lgkmcnt(0)\n\ts_barrier" ::: "memory");
}

// ---- prep: materialize normalized Toeplitz A fragments per cell into d_ws ----
__global__ __launch_bounds__(256) void pb_prep_kernel(
    const float* __restrict__ kern, unsigned int* __restrict__ aws)
{
    const int cell = blockIdx.x;           // cj*4+ci
    const int tid  = threadIdx.x;
    const int lane = tid & 63;
    const float* kp = kern + cell * (KS * KS);

    float s = 0.f;
    #pragma unroll
    for (int i = 0; i < 4; ++i) {
        int t = lane + 64 * i;
        s += (t < KS * KS) ? kp[t] : 0.f;
    }
    #pragma unroll
    for (int m = 1; m < 64; m <<= 1) s += __shfl_xor(s, m, 64);
    const float inv = 1.0f / (s + 1e-12f);

    const int i  = tid >> 4;               // x-position (A row)
    const int k2 = tid & 15;               // half-pair index
    unsigned int* wp = aws + cell * (AWS_CELL_BYTES / 4) + tid;

    for (int dy = 0; dy < KS; ++dy) {
        float v0 = 0.f, v1 = 0.f;
        int dx0 = 2 * k2 - i - 1;          // A[i][k] = kh[k-i-1]
        int dx1 = dx0 + 1;
        if (dx0 >= 0 && dx0 < KS) v0 = kp[dy * KS + dx0] * inv;
        if (dx1 >= 0 && dx1 < KS) v1 = kp[dy * KS + dx1] * inv;
        f16x4 h; h[0] = (_Float16)v0; h[1] = (_Float16)v1; h[2] = 0; h[3] = 0;
        unsigned long long u = __builtin_bit_cast(unsigned long long, h);
        wp[dy * 256] = (unsigned int)u;
    }
}

// ---- main: R24 configuration (session best, 48.19 us).
// R25 (persistent 768-grid, plane-pairs) regressed: spill (WRITE +56 MB
// scratch) + L2 locality loss (FETCH 51->84 MB). Reverted.
// Structure: 256-row rolling block, 16-iter pipeline, write-early chunk
// landing, light barriers, af[15] pinned resident, XCD swizzle with 192
// contiguous blocks (= 3 complete planes) per XCD.
__global__ __launch_bounds__(256, 4) void pb_mfma_kernel(
    const float* __restrict__ x,
    const unsigned int* __restrict__ aws,
    float* __restrict__ out)
{
    __shared__ __align__(16) _Float16 s_tile[TROWS * TCOLS];   // 22720 B

    const int tid  = threadIdx.x;
    const int lane = tid & 63;
    const int w    = tid >> 6;           // wave id: x sub-block
    const int g    = lane >> 4;          // k-group 0..3
    const int cc   = lane & 15;          // A-row / B-col index

    // T1 swizzle: bijective for NWG % 8 == 0; each XCD gets 192 contiguous
    // blocks = 3 complete planes -> input halo + A-table are XCD-local L2
    // hits (FETCH 87->51 MB, R22).
    const int bid = blockIdx.x;
    const int sw  = (bid & 7) * (NWG / 8) + (bid >> 3);
    const int sbx = sw & 15;             // 16 x-strips
    const int sby = (sw >> 4) & 3;       // 4 cell-rows
    const int sbz = sw >> 6;             // 24 planes

    const int bx0 = sbx * BX;
    const int ci  = sbx >> 2;            // cell col
    const int cj  = sby;                 // cell row
    const int bc  = sbz;                 // plane (b*c)

    const int cellx0 = ci * CELL;
    const int celly0 = cj * CELL, celly1 = celly0 + CELL - 1;

    const float* plane = x + (size_t)bc * HH * WW;

    // ---- A fragments: 15 coalesced dwordx4 loads, pinned resident (R8) ----
    const u32x4* ap = (const u32x4*)(aws + (cj * 4 + ci) * (AWS_CELL_BYTES / 4))
                      + cc * 4 + g;
    u32x4 af[KS];
    #pragma unroll
    for (int dy = 0; dy < KS; ++dy) af[dy] = ap[dy * 64];
    #pragma unroll
    for (int dy = 0; dy < KS; ++dy) asm volatile("" : "+v"(af[dy]));

    // ---- staging helpers ----
    auto stage_addr = [&](int strip, int lc, int idx) -> const float* {
        int r20  = idx / 20;
        int c4   = idx - r20 * 20;
        int row  = lc * 16 + r20;                       // tile row 0..141
        int gy   = min(max(celly0 + strip * 128 - PAD + row, celly0), celly1);
        int gx0  = bx0 - 8 + 4 * c4;
        int gx0c = min(max(gx0, cellx0), cellx0 + CELL - 4);
        return plane + (size_t)gy * WW + gx0c;
    };
    auto write_group = [&](int lc, int idx, float4 v) {
        int r20 = idx / 20;
        int c4  = idx - r20 * 20;
        int row = lc * 16 + r20;
        int gx0 = bx0 - 8 + 4 * c4;
        bool lo = gx0 <  cellx0;
        bool hi = gx0 >  cellx0 + CELL - 4;
        float e0 = hi ? v.w : v.x;
        float e1 = lo ? v.x : (hi ? v.w : v.y);
        float e2 = lo ? v.x : (hi ? v.w : v.z);
        float e3 = lo ? v.x : v.w;
        f16x4 h;
        h[0] = (_Float16)e0; h[1] = (_Float16)e1;
        h[2] = (_Float16)e2; h[3] = (_Float16)e3;
        *(f16x4*)(s_tile + row * TCOLS + 4 * c4) = h;   // ds_write_b64
    };
    auto issue_chunk = [&](int c, float4& v0, float4& v1, bool& h1) {
        int strip = c >= 9;
        int lc    = c - 9 * strip;
        int ng    = (lc == 8) ? 280 : 320;
        v0 = *(const float4*)stage_addr(strip, lc, tid);
        h1 = 256 + tid < ng;
        if (h1) v1 = *(const float4*)stage_addr(strip, lc, 256 + tid);
    };
    auto write_chunk = [&](int c, float4 v0, float4 v1, bool h1) {
        int strip = c >= 9;
        int lc    = c - 9 * strip;
        (void)strip;
        write_group(lc, tid, v0);
        if (h1) write_group(lc, 256 + tid, v1);
    };

    // ---- prologue: stage chunks 0..2; issue 3,4 as 2-deep pending ----
    {
        float4 a0, a1, b0, b1, c0, c1; bool ha1, hb1, hc1;
        issue_chunk(0, a0, a1, ha1);
        issue_chunk(1, b0, b1, hb1);
        issue_chunk(2, c0, c1, hc1);
        write_chunk(0, a0, a1, ha1);
        write_chunk(1, b0, b1, hb1);
        write_chunk(2, c0, c1, hc1);
    }
    float4 pA0, pA1, pB0, pB1; bool hA1, hB1;
    issue_chunk(3, pA0, pA1, hA1);
    issue_chunk(4, pB0, pB1, hB1);
    light_barrier();

    // ---- rolling main loop: 16 iterations (2 strips x 8 patches) ----
    const _Float16* bbase = s_tile + cc * TCOLS + w * 16 + g * 8;
    float* oplane = out + (size_t)bc * HH * WW;

    #pragma unroll
    for (int t = 0; t < NITER; ++t) {
        const int strip = t >> 3;
        const int jpl   = t & 7;

        // WRITE-EARLY: land pending chunk t+3 first (rows disjoint from
        // patch t's reads; its loads are 2 iters old -> vmcnt wait free).
        if (t + 3 < CHN) write_chunk(t + 3, pA0, pA1, hA1);

        // issue chunk t+5 (written at iter t+2: two iterations of cover)
        float4 n0 = {0,0,0,0}, n1 = {0,0,0,0}; bool hn1 = false;
        if (t + 5 < CHN) issue_chunk(t + 5, n0, n1, hn1);

        // compute patch: reads tile rows 16*jpl .. 16*jpl+30
        __builtin_amdgcn_s_setprio(1);
        f32x4 acc0 = {0.f, 0.f, 0.f, 0.f};
        f32x4 acc1 = {0.f, 0.f, 0.f, 0.f};
        #pragma unroll
        for (int dy = 0; dy < KS; ++dy) {
            f16x8 b = *(const f16x8*)(bbase + (16 * jpl + dy) * TCOLS);
            if (dy & 1)
                acc1 = __builtin_amdgcn_mfma_f32_16x16x32_f16(
                           __builtin_bit_cast(f16x8, af[dy]), b, acc1, 0, 0, 0);
            else
                acc0 = __builtin_amdgcn_mfma_f32_16x16x32_f16(
                           __builtin_bit_cast(f16x8, af[dy]), b, acc0, 0, 0, 0);
        }
        __builtin_amdgcn_s_setprio(0);
        f32x4 r = acc0 + acc1;
        // D: col=lane&15 (image row), row=4*(lane>>4)+e (x position)
        float* op = oplane
                  + (size_t)(celly0 + strip * 128 + 16 * jpl + cc) * WW
                  + bx0 + 16 * w + 4 * g;
        *(f32x4*)op = r;   // plain store: L2 merges the 64B/row segments

        light_barrier();

        // rotate pending
        pA0 = pB0; pA1 = pB1; hA1 = hB1;
        pB0 = n0;  pB1 = n1;  hB1 = hn1;
    }
}

extern "C" void kernel_launch(void* const* d_in, const int* in_sizes, int n_in,
                              void* d_out, int out_size, void* d_ws, size_t ws_size,
                              hipStream_t stream) {
    (void)in_sizes; (void)n_in; (void)ws_size; (void)out_size;
    const float* x    = (const float*)d_in[0];
    const float* kern = (const float*)d_in[1];
    float* out        = (float*)d_out;
    unsigned int* aws = (unsigned int*)d_ws;   // 16 cells x 15 KiB = 240 KiB

    pb_prep_kernel<<<16, 256, 0, stream>>>(kern, aws);
    pb_mfma_kernel<<<NWG, 256, 0, stream>>>(x, aws, out);   // 1D grid, swizzled inside
}